// Round 3
// baseline (484.092 us; speedup 1.0000x reference)
//
#include <hip/hip_runtime.h>
#include <hip/hip_bf16.h>
#include <math.h>

#define BB 4
#define QQ 75
#define NBQ 300        // BB*QQ
#define CC 640
#define HW 121
#define NW 5
#define KS 5
#define SS 25          // NW*KS
#define MS 605         // KS*HW
#define JT 3025        // NW*MS
#define BQ_PER_XCD 38  // ceil(300/8)

typedef __attribute__((ext_vector_type(8))) short short8;
typedef __attribute__((ext_vector_type(4))) float f32x4;

// workspace float offsets
#define OFF_SBF   0
#define SBF_F     (BB*JT*CC/2)            // bf16 storage
#define OFF_QBF   (OFF_SBF + SBF_F)
#define QBF_F     (NBQ*HW*CC/2)
#define OFF_P     (OFF_QBF + QBF_F)       // float4 partials [300][5][121]

__device__ __forceinline__ void async16(const void* g, void* l) {
    __builtin_amdgcn_global_load_lds(
        (const __attribute__((address_space(1))) unsigned int*)g,
        (__attribute__((address_space(3))) unsigned int*)l, 16, 0, 0);
}

// ---------------------------------------------------------------------------
// Fused: norm (pass 1, HBM-stream, 16 outstanding loads/thread) +
// normalize/cast/transpose (pass 2, cache-hot). One block per descriptor
// column. Output [col][hw][c] bf16. Block 0 also zeroes d_out.
__global__ void prep_kernel(const float* __restrict__ sup, const float* __restrict__ qry,
                            __hip_bfloat16* __restrict__ Sbf, __hip_bfloat16* __restrict__ Qbf,
                            float* __restrict__ out)
{
    const int col = blockIdx.x;      // 0..399
    const int t   = threadIdx.x;     // 256
    if (col == 0 && t == 0) out[0] = 0.f;   // replaces memset dispatch
    const float* src;
    __hip_bfloat16* dst;
    if (col < BB * SS) {
        const int b = col / SS, s = col % SS;
        const int n = s / KS, k = s % KS;
        src = sup + (size_t)col * (CC * HW);
        dst = Sbf + ((size_t)b * JT + n * MS + k * HW) * CC;
    } else {
        const int bq = col - BB * SS;
        src = qry + (size_t)bq * (CC * HW);
        dst = Qbf + (size_t)bq * (HW * CC);
    }

    __shared__ float inv[128];
    __shared__ float T[32][128];

    // ---- phase 1: sum of squares per hw (2 c-interleaved threads, 2 accs) ----
    const int cc2 = t >> 7, hw1 = t & 127;
    float ss0 = 0.f, ss1 = 0.f;
    if (hw1 < HW) {
        const float* p = src + hw1;
#pragma unroll 16
        for (int c = cc2; c < CC; c += 4) {
            float v0 = p[(size_t)c * HW];
            float v1 = p[(size_t)(c + 2) * HW];
            ss0 = fmaf(v0, v0, ss0);
            ss1 = fmaf(v1, v1, ss1);
        }
    }
    T[cc2][hw1] = ss0 + ss1;
    __syncthreads();
    if (t < 128) inv[t] = (t < HW) ? 1.f / (sqrtf(T[0][t] + T[1][t]) + 1e-8f) : 0.f;

    // ---- phase 2: scale + transpose + bf16 write ----
    for (int c0 = 0; c0 < CC; c0 += 32) {
        __syncthreads();
#pragma unroll
        for (int i = 0; i < 16; ++i) {
            int idx = t + i * 256;
            int cc = idx >> 7, hw = idx & 127;
            if (hw < 128 && hw < HW) T[cc][hw] = src[(size_t)(c0 + cc) * HW + hw] * inv[hw];
        }
        __syncthreads();
        const int hw = t >> 1, half = t & 1;
        if (hw < HW) {
            __hip_bfloat16 hv[16];
#pragma unroll
            for (int i = 0; i < 16; ++i) hv[i] = __float2bfloat16(T[half * 16 + i][hw]);
            int4* op = reinterpret_cast<int4*>(dst + (size_t)hw * CC + c0 + half * 16);
            op[0] = reinterpret_cast<int4*>(hv)[0];
            op[1] = reinterpret_cast<int4*>(hv)[1];
        }
    }
}

// ---------------------------------------------------------------------------
// Per (bq, n): MFMA cosine GEMM [121 x 605], register-resident top3/argmax.
// R2 change: k-chunk 64 -> 32. LDS drops 64 KB -> 32 KB (2 x (8+8) KB) and
// live fragments 16 -> 8 (combined VGPR+AGPR ~140 < 170), so with
// __launch_bounds__(256,3) the CU fits 3 blocks = 12 waves (was 8): the
// counters showed no pipe >50% busy -> latency-bound, occupancy is the lever.
// Swizzle re-derived for 64 B rows (4 x 16 B slots):
//   write: lane l -> row base16+(l>>2), slot l&3, k-block kb=(l&3)^((l>>3)&3)
//   read : lane (l4,l15) row base+l15 -> slot = l4 ^ ((l15>>1)&3)
// -> 2 lanes/bank per b128 (free, same property as the 128 B-row scheme).
// Counted-vmcnt pipeline: STAGE(next,4 loads); vmcnt(4); barrier; 8 ds_reads;
// 16 MFMA; barrier. 100 chunks; epilogue every 20th.
__launch_bounds__(256, 3)
__global__ void simi_kernel(const __hip_bfloat16* __restrict__ Sbf,
                            const __hip_bfloat16* __restrict__ Qbf,
                            float4* __restrict__ pout)
{
    const int xcd   = blockIdx.x & 7;
    const int local = blockIdx.x >> 3;      // 0..189
    const int n     = local % NW;
    const int bq    = xcd * BQ_PER_XCD + local / NW;
    if (bq >= NBQ) return;
    const int b   = bq / QQ;
    const int tid = threadIdx.x;
    const int lane = tid & 63, wid = tid >> 6;
    const int l15 = lane & 15, l4 = lane >> 4;
    const int wr0 = (wid & 1) * 64;    // wave row base
    const int wc0 = (wid >> 1) * 64;   // wave col base (tile-local)

    const unsigned short* qbase = (const unsigned short*)(Qbf + (size_t)bq * (HW * CC));
    const unsigned short* sbase = (const unsigned short*)(Sbf + ((size_t)b * JT + n * MS) * CC);

    __shared__ __align__(16) unsigned short AsBuf[2][128 * 32];  // 2 x 8 KB
    __shared__ __align__(16) unsigned short BsBuf[2][128 * 32];  // 2 x 8 KB  (32 KB total)

    const int srow = lane >> 2;              // row within 16-row group (0..15)
    const int kb   = (lane & 3) ^ ((lane >> 3) & 3);  // swizzled k-block (0..3)
    // A global offsets for the 2 row-groups this wave stages (row clamped)
    int aoff2[2];
#pragma unroll
    for (int g = 0; g < 2; ++g) {
        int arow = wid * 32 + g * 16 + srow;
        int grow = arow < HW ? arow : HW - 1;
        aoff2[g] = grow * CC + kb * 8;
    }
    // B row index base for the 2 groups (ms0 added per stage)
    int jb2[2];
#pragma unroll
    for (int g = 0; g < 2; ++g) jb2[g] = wid * 32 + g * 16 + srow;

    const int ldso_base = wid * 2048 + lane * 16;   // byte offset in 8 KB buffer

    // stage one (ms0, c0) chunk (k=32) into buffer nb: 4 async16 per wave
#define STAGE(ms0_, c0_, nb_)                                                        \
    {                                                                                \
        _Pragma("unroll")                                                            \
        for (int g = 0; g < 2; ++g) {                                                \
            const int ldso = ldso_base + g * 1024;                                   \
            async16(qbase + aoff2[g] + (c0_), (char*)&AsBuf[nb_][0] + ldso);         \
            int j_ = (ms0_) + jb2[g];                                                \
            int jc_ = j_ < MS ? j_ : MS - 1;                                         \
            async16(sbase + jc_ * CC + kb * 8 + (c0_), (char*)&BsBuf[nb_][0] + ldso);\
        }                                                                            \
    }

    float rt0[16], rt1[16], rt2[16]; int ra[16];
#pragma unroll
    for (int i = 0; i < 16; ++i) { rt0[i] = -INFINITY; rt1[i] = -INFINITY; rt2[i] = -INFINITY; ra[i] = 0; }

    f32x4 acc[4][4];
#pragma unroll
    for (int mi = 0; mi < 4; ++mi)
#pragma unroll
        for (int ni = 0; ni < 4; ++ni)
#pragma unroll
            for (int r = 0; r < 4; ++r) acc[mi][ni][r] = 0.f;

    // prologue: stage chunk 0
    STAGE(0, 0, 0);
    int nb = 0;

    const int slot = l4 ^ ((l15 >> 1) & 3);           // read slot (0..3)
    const int aro  = (wr0 + l15) * 32 + slot * 8;     // ushort idx, + mi*512
    const int bro  = (wc0 + l15) * 32 + slot * 8;     // ushort idx, + ni*512

    // flat pipelined loop: chunk t -> ms0=(t/20)*128, c0=(t%20)*32
    for (int t = 0; t < 100; ++t) {
        const int tn = t + 1;
        if (tn < 100) {
            const int nms = (tn / 20) * 128;
            const int nc  = (tn % 20) * 32;
            STAGE(nms, nc, nb ^ 1);
            // wait only for chunk-t's 4 loads (issued one full iteration ago);
            // the 4 just-issued prefetch loads stay in flight across the barrier
            asm volatile("s_waitcnt vmcnt(4)" ::: "memory");
        } else {
            asm volatile("s_waitcnt vmcnt(0)" ::: "memory");
        }
        __builtin_amdgcn_s_barrier();   // buffer nb fully resident for all waves

        // ---- compute from buffer nb: 8 fragment reads, 16 MFMA ----
        short8 af[4], bf[4];
#pragma unroll
        for (int mi = 0; mi < 4; ++mi)
            af[mi] = *(const short8*)(&AsBuf[nb][0] + aro + mi * 512);
#pragma unroll
        for (int ni = 0; ni < 4; ++ni)
            bf[ni] = *(const short8*)(&BsBuf[nb][0] + bro + ni * 512);

        __builtin_amdgcn_s_setprio(1);
#pragma unroll
        for (int mi = 0; mi < 4; ++mi)
#pragma unroll
            for (int ni = 0; ni < 4; ++ni)
                acc[mi][ni] = __builtin_amdgcn_mfma_f32_16x16x32_bf16(
                    af[mi], bf[ni], acc[mi][ni], 0, 0, 0);
        __builtin_amdgcn_s_setprio(0);
        nb ^= 1;

        if ((t % 20) == 19) {
            const int ms0 = (t / 20) * 128;
            // in-register epilogue: ascending j keeps first-max tie rule
            int jg[4]; bool jvalid[4];
#pragma unroll
            for (int nf = 0; nf < 4; ++nf) {
                const int jl = ms0 + wc0 + nf * 16 + l15;
                jvalid[nf] = (jl < MS);
                jg[nf] = n * MS + jl;
            }
#pragma unroll
            for (int mi = 0; mi < 4; ++mi)
#pragma unroll
                for (int nf = 0; nf < 4; ++nf)
#pragma unroll
                    for (int r = 0; r < 4; ++r) {
                        const int si = mi * 4 + r;
                        float v = jvalid[nf] ? acc[mi][nf][r] : -INFINITY;
                        const bool gt = v > rt0[si];
                        ra[si] = gt ? jg[nf] : ra[si];
                        const float m1 = fminf(rt0[si], v);
                        rt0[si] = fmaxf(rt0[si], v);
                        const float m2 = fminf(rt1[si], m1);
                        rt1[si] = fmaxf(rt1[si], m1);
                        rt2[si] = fmaxf(rt2[si], m2);
                    }
            // re-zero accumulators for the next ms0 block
#pragma unroll
            for (int mi = 0; mi < 4; ++mi)
#pragma unroll
                for (int ni = 0; ni < 4; ++ni)
#pragma unroll
                    for (int r = 0; r < 4; ++r) acc[mi][ni][r] = 0.f;
        }

        __builtin_amdgcn_s_barrier();   // all reads of buffer nb^1 done before
                                        // anyone overwrites it next iteration
    }

    // butterfly merge across the 16 lanes of each col-group (masks 1,2,4,8)
#pragma unroll
    for (int si = 0; si < 16; ++si) {
#pragma unroll
        for (int mask = 1; mask <= 8; mask <<= 1) {
            const float o0 = __shfl_xor(rt0[si], mask);
            const float o1 = __shfl_xor(rt1[si], mask);
            const float o2 = __shfl_xor(rt2[si], mask);
            const int   oa = __shfl_xor(ra[si],  mask);
            const bool take = (o0 > rt0[si]) || (o0 == rt0[si] && oa < ra[si]);
            ra[si] = take ? oa : ra[si];
            float m1 = fminf(rt0[si], o0); rt0[si] = fmaxf(rt0[si], o0);
            float m2 = fminf(rt1[si], m1); rt1[si] = fmaxf(rt1[si], m1);
            rt2[si] = fmaxf(rt2[si], m2);
            m1 = fminf(rt0[si], o1); rt0[si] = fmaxf(rt0[si], o1);
            m2 = fminf(rt1[si], m1); rt1[si] = fmaxf(rt1[si], m1);
            rt2[si] = fmaxf(rt2[si], m2);
            m1 = fminf(rt0[si], o2); rt0[si] = fmaxf(rt0[si], o2);
            m2 = fminf(rt1[si], m1); rt1[si] = fmaxf(rt1[si], m1);
            rt2[si] = fmaxf(rt2[si], m2);
        }
    }

    // select this lane's slot (si == l15)
    float s0 = rt0[0], s1 = rt1[0], s2 = rt2[0]; int sa = ra[0];
#pragma unroll
    for (int i = 1; i < 16; ++i) {
        const bool p = (l15 == i);
        s0 = p ? rt0[i] : s0; s1 = p ? rt1[i] : s1; s2 = p ? rt2[i] : s2; sa = p ? ra[i] : sa;
    }
    const int m = wr0 + (l15 >> 2) * 16 + l4 * 4 + (l15 & 3);

    // cross-wave (col-half) merge via LDS overlay on the dead tile buffers
    __syncthreads();                       // all tile reads done -> safe to overlay
    float4* mbuf = (float4*)&AsBuf[0][0];
    if ((wid >> 1) == 0) {
        float4 v; v.x = s0; v.y = s1; v.z = s2; v.w = __int_as_float(sa);
        mbuf[m] = v;
    }
    __syncthreads();
    if ((wid >> 1) == 1) {
        const float4 o = mbuf[m];
        const int oa = __float_as_int(o.w);
        const bool take = (o.x > s0) || (o.x == s0 && oa < sa);
        sa = take ? oa : sa;
        float m1 = fminf(s0, o.x); s0 = fmaxf(s0, o.x);
        float m2 = fminf(s1, m1);  s1 = fmaxf(s1, m1);
        s2 = fmaxf(s2, m2);
        m1 = fminf(s0, o.y); s0 = fmaxf(s0, o.y);
        m2 = fminf(s1, m1);  s1 = fmaxf(s1, m1);
        s2 = fmaxf(s2, m2);
        m1 = fminf(s0, o.z); s0 = fmaxf(s0, o.z);
        m2 = fminf(s1, m1);  s1 = fmaxf(s1, m1);
        s2 = fmaxf(s2, m2);
        if (m < HW) {
            float4 v; v.x = s0; v.y = s1; v.z = s2; v.w = __int_as_float(sa);
            pout[(bq * NW + n) * HW + m] = v;
        }
    }
#undef STAGE
}

// ---------------------------------------------------------------------------
// Merge 5 per-n partials, mutual-NN mask, logits, per-query CE, atomic mean.
__global__ void merge_kernel(const float4* __restrict__ pout, const int* __restrict__ qy,
                             float* __restrict__ out)
{
    const int bq  = blockIdx.x;
    const int tid = threadIdx.x;   // 128 threads

    __shared__ float cw[128];
    __shared__ int   ag[128];
    __shared__ float tv[NW][128];
    __shared__ float maskf[128];
    __shared__ float lg[8];

    if (tid < HW) {
        float g0 = -INFINITY; int garg = 0;
#pragma unroll
        for (int n = 0; n < NW; ++n) {
            const float4 a = pout[(bq * NW + n) * HW + tid];
            if (a.x > g0) { g0 = a.x; garg = __float_as_int(a.w); }   // asc n = asc j
            tv[n][tid] = (a.x + a.y + a.z) * (1.f / 3.f);
        }
        cw[tid] = g0 + 1.0f;   // class_wise_max
        ag[tid] = garg;        // query_nearest (global j)
    }
    __syncthreads();
    if (tid < HW) {
        const float mycw = cw[tid];
        const int   myag = ag[tid];
        float ok = 1.f;
        for (int m2 = 0; m2 < HW; ++m2) {
            if (m2 == tid) continue;
            if (ag[m2] == myag) {
                float c2 = cw[m2];
                if (c2 > mycw || (c2 == mycw && m2 < tid)) ok = 0.f;  // first-max over mq
            }
        }
        maskf[tid] = ok;
    }
    __syncthreads();
    if (tid < NW) {
        float s = 0.f;
        for (int mq = 0; mq < HW; ++mq) s += maskf[mq] * tv[tid][mq];
        lg[tid] = s * 0.5f;   // / TEMPERATURE
    }
    __syncthreads();
    if (tid == 0) {
        float m = lg[0];
#pragma unroll
        for (int n2 = 1; n2 < NW; ++n2) m = fmaxf(m, lg[n2]);
        float se = 0.f;
#pragma unroll
        for (int n2 = 0; n2 < NW; ++n2) se += expf(lg[n2] - m);
        int y = qy[bq];
        atomicAdd(out, -(lg[y] - m - logf(se)) * (1.f / NBQ));
    }
}

// ---------------------------------------------------------------------------
extern "C" void kernel_launch(void* const* d_in, const int* in_sizes, int n_in,
                              void* d_out, int out_size, void* d_ws, size_t ws_size,
                              hipStream_t stream)
{
    const float* sup = (const float*)d_in[0];   // [4][25][640][121]
    const float* qry = (const float*)d_in[1];   // [4][75][640][121]
    const int*   qy  = (const int*)d_in[3];     // [4][75]
    float* out = (float*)d_out;
    float* ws  = (float*)d_ws;

    __hip_bfloat16* Sbf = (__hip_bfloat16*)(ws + OFF_SBF);
    __hip_bfloat16* Qbf = (__hip_bfloat16*)(ws + OFF_QBF);
    float4* pout = (float4*)(ws + OFF_P);

    hipLaunchKernelGGL(prep_kernel, dim3(BB * SS + NBQ), dim3(256), 0, stream,
                       sup, qry, Sbf, Qbf, out);
    hipLaunchKernelGGL(simi_kernel, dim3(8 * BQ_PER_XCD * NW), dim3(256), 0, stream,
                       Sbf, Qbf, pout);
    hipLaunchKernelGGL(merge_kernel, dim3(NBQ), dim3(128), 0, stream, pout, qy, out);
}

// Round 4
// 408.299 us; speedup vs baseline: 1.1856x; 1.1856x over previous
//
#include <hip/hip_runtime.h>
#include <hip/hip_bf16.h>
#include <math.h>

#define BB 4
#define QQ 75
#define NBQ 300        // BB*QQ
#define CC 640
#define HW 121
#define NW 5
#define KS 5
#define SS 25          // NW*KS
#define MS 605         // KS*HW
#define JT 3025        // NW*MS
#define BQ_PER_XCD 38  // ceil(300/8)

typedef __attribute__((ext_vector_type(8))) short short8;
typedef __attribute__((ext_vector_type(4))) float f32x4;

// workspace float offsets
#define OFF_SBF   0
#define SBF_F     (BB*JT*CC/2)            // bf16 storage
#define OFF_QBF   (OFF_SBF + SBF_F)
#define QBF_F     (NBQ*HW*CC/2)
#define OFF_P     (OFF_QBF + QBF_F)       // float4 partials [300][5][121]

__device__ __forceinline__ void async16(const void* g, void* l) {
    __builtin_amdgcn_global_load_lds(
        (const __attribute__((address_space(1))) unsigned int*)g,
        (__attribute__((address_space(3))) unsigned int*)l, 16, 0, 0);
}

// ---------------------------------------------------------------------------
// Fused: norm (pass 1, HBM-stream, 16 outstanding loads/thread) +
// normalize/cast/transpose (pass 2, cache-hot). One block per descriptor
// column. Output [col][hw][c] bf16. Block 0 also zeroes d_out.
__global__ void prep_kernel(const float* __restrict__ sup, const float* __restrict__ qry,
                            __hip_bfloat16* __restrict__ Sbf, __hip_bfloat16* __restrict__ Qbf,
                            float* __restrict__ out)
{
    const int col = blockIdx.x;      // 0..399
    const int t   = threadIdx.x;     // 256
    if (col == 0 && t == 0) out[0] = 0.f;   // replaces memset dispatch
    const float* src;
    __hip_bfloat16* dst;
    if (col < BB * SS) {
        const int b = col / SS, s = col % SS;
        const int n = s / KS, k = s % KS;
        src = sup + (size_t)col * (CC * HW);
        dst = Sbf + ((size_t)b * JT + n * MS + k * HW) * CC;
    } else {
        const int bq = col - BB * SS;
        src = qry + (size_t)bq * (CC * HW);
        dst = Qbf + (size_t)bq * (HW * CC);
    }

    __shared__ float inv[128];
    __shared__ float T[32][128];

    // ---- phase 1: sum of squares per hw (2 c-interleaved threads, 2 accs) ----
    const int cc2 = t >> 7, hw1 = t & 127;
    float ss0 = 0.f, ss1 = 0.f;
    if (hw1 < HW) {
        const float* p = src + hw1;
#pragma unroll 16
        for (int c = cc2; c < CC; c += 4) {
            float v0 = p[(size_t)c * HW];
            float v1 = p[(size_t)(c + 2) * HW];
            ss0 = fmaf(v0, v0, ss0);
            ss1 = fmaf(v1, v1, ss1);
        }
    }
    T[cc2][hw1] = ss0 + ss1;
    __syncthreads();
    if (t < 128) inv[t] = (t < HW) ? 1.f / (sqrtf(T[0][t] + T[1][t]) + 1e-8f) : 0.f;

    // ---- phase 2: scale + transpose + bf16 write ----
    for (int c0 = 0; c0 < CC; c0 += 32) {
        __syncthreads();
#pragma unroll
        for (int i = 0; i < 16; ++i) {
            int idx = t + i * 256;
            int cc = idx >> 7, hw = idx & 127;
            if (hw < HW) T[cc][hw] = src[(size_t)(c0 + cc) * HW + hw] * inv[hw];
        }
        __syncthreads();
        const int hw = t >> 1, half = t & 1;
        if (hw < HW) {
            __hip_bfloat16 hv[16];
#pragma unroll
            for (int i = 0; i < 16; ++i) hv[i] = __float2bfloat16(T[half * 16 + i][hw]);
            int4* op = reinterpret_cast<int4*>(dst + (size_t)hw * CC + c0 + half * 16);
            op[0] = reinterpret_cast<int4*>(hv)[0];
            op[1] = reinterpret_cast<int4*>(hv)[1];
        }
    }
}

// ---------------------------------------------------------------------------
// Per (bq, n): MFMA cosine GEMM [121 x 605], register-resident top3/argmax.
// Frame = R1's verified config (k-chunk 64, 64 KB LDS, 2 blocks/CU, counted
// vmcnt(8), 50 flat chunks). R3 change: WAVE-PARITY STAGGER. The R1 counters
// showed LDS-pipe work (~2050 cyc/chunk/CU) and matrix work (~1242) summing
// to the 3816-cyc wall -> pipes alternate, never co-busy, because both
// barriers release all waves into read-phase simultaneously. Even waves now
// compute k-half 0 then 1; odd waves 1 then 0 -> at any instant ~half the
// waves are on ds_read while the others run MFMA. setprio(1) around each
// MFMA cluster gives the scheduler the role-diversity to exploit it.
// (R2's (256,3) squeeze spilled top-3 state to scratch: WRITE_SIZE 2.8->43MB.
// Reverted; only one 8-frag set is live at a time here, VGPR stays low.)
__launch_bounds__(256, 2)
__global__ void simi_kernel(const __hip_bfloat16* __restrict__ Sbf,
                            const __hip_bfloat16* __restrict__ Qbf,
                            float4* __restrict__ pout)
{
    const int xcd   = blockIdx.x & 7;
    const int local = blockIdx.x >> 3;      // 0..189
    const int n     = local % NW;
    const int bq    = xcd * BQ_PER_XCD + local / NW;
    if (bq >= NBQ) return;
    const int b   = bq / QQ;
    const int tid = threadIdx.x;
    const int lane = tid & 63, wid = tid >> 6;
    const int l15 = lane & 15, l4 = lane >> 4;
    const int wr0 = (wid & 1) * 64;    // wave row base
    const int wc0 = (wid >> 1) * 64;   // wave col base (tile-local)

    const unsigned short* qbase = (const unsigned short*)(Qbf + (size_t)bq * (HW * CC));
    const unsigned short* sbase = (const unsigned short*)(Sbf + ((size_t)b * JT + n * MS) * CC);

    __shared__ __align__(16) unsigned short AsBuf[2][128 * 64];  // 2 x 16 KB
    __shared__ __align__(16) unsigned short BsBuf[2][128 * 64];  // 2 x 16 KB  (64 KB total)

    const int srow = lane >> 3;              // row within 8-row segment
    const int kb   = (lane & 7) ^ srow;      // swizzled k-block held by this lane
    int aoff[4];
#pragma unroll
    for (int p = 0; p < 4; ++p) {
        int arow = wid * 32 + p * 8 + srow;
        int grow = arow < HW ? arow : HW - 1;
        aoff[p] = grow * CC + kb * 8;
    }
    const int ldso_base = wid * 4096 + lane * 16;

    // stage one (ms0, c0) chunk into buffer nb
#define STAGE(ms0_, c0_, nb_)                                                        \
    {                                                                                \
        _Pragma("unroll")                                                            \
        for (int p = 0; p < 4; ++p) {                                                \
            const int ldso = ldso_base + p * 1024;                                   \
            async16(qbase + aoff[p] + (c0_), (char*)&AsBuf[nb_][0] + ldso);          \
            int j_ = (ms0_) + wid * 32 + p * 8 + srow;                               \
            int jc_ = j_ < MS ? j_ : MS - 1;                                         \
            async16(sbase + jc_ * CC + kb * 8 + (c0_), (char*)&BsBuf[nb_][0] + ldso);\
        }                                                                            \
    }

    float rt0[16], rt1[16], rt2[16]; int ra[16];
#pragma unroll
    for (int i = 0; i < 16; ++i) { rt0[i] = -INFINITY; rt1[i] = -INFINITY; rt2[i] = -INFINITY; ra[i] = 0; }

    f32x4 acc[4][4];
#pragma unroll
    for (int mi = 0; mi < 4; ++mi)
#pragma unroll
        for (int ni = 0; ni < 4; ++ni)
#pragma unroll
            for (int r = 0; r < 4; ++r) acc[mi][ni][r] = 0.f;

    // prologue: stage chunk 0
    STAGE(0, 0, 0);
    int nb = 0;

    // wave-parity stagger: even waves do k-half 0 first, odd waves half 1
    const int ksF = wid & 1;
    const int slotF = (ksF * 4 + l4) ^ (l15 & 7);          // first half's slot
    const int slotS = (((ksF ^ 1) * 4) + l4) ^ (l15 & 7);  // second half's slot

    // flat pipelined loop: chunk t -> ms0=(t/10)*128, c0=(t%10)*64
    for (int t = 0; t < 50; ++t) {
        const int tn = t + 1;
        if (tn < 50) {
            const int nms = (tn / 10) * 128;
            const int nc  = (tn % 10) * 64;
            STAGE(nms, nc, nb ^ 1);
            // wait only for chunk-t's 8 loads (issued one full iteration ago);
            // the 8 just-issued prefetch loads stay in flight across the barrier
            asm volatile("s_waitcnt vmcnt(8)" ::: "memory");
        } else {
            asm volatile("s_waitcnt vmcnt(0)" ::: "memory");
        }
        __builtin_amdgcn_s_barrier();   // buffer nb fully resident for all waves

        short8 af[4], bf[4];
        // ---- k-half F (parity-dependent) ----
#pragma unroll
        for (int mi = 0; mi < 4; ++mi)
            af[mi] = *(const short8*)(&AsBuf[nb][0] + (wr0 + mi * 16 + l15) * 64 + slotF * 8);
#pragma unroll
        for (int ni = 0; ni < 4; ++ni)
            bf[ni] = *(const short8*)(&BsBuf[nb][0] + (wc0 + ni * 16 + l15) * 64 + slotF * 8);
        __builtin_amdgcn_s_setprio(1);
#pragma unroll
        for (int mi = 0; mi < 4; ++mi)
#pragma unroll
            for (int ni = 0; ni < 4; ++ni)
                acc[mi][ni] = __builtin_amdgcn_mfma_f32_16x16x32_bf16(
                    af[mi], bf[ni], acc[mi][ni], 0, 0, 0);
        __builtin_amdgcn_s_setprio(0);
        // ---- k-half S (the other one) ----
#pragma unroll
        for (int mi = 0; mi < 4; ++mi)
            af[mi] = *(const short8*)(&AsBuf[nb][0] + (wr0 + mi * 16 + l15) * 64 + slotS * 8);
#pragma unroll
        for (int ni = 0; ni < 4; ++ni)
            bf[ni] = *(const short8*)(&BsBuf[nb][0] + (wc0 + ni * 16 + l15) * 64 + slotS * 8);
        __builtin_amdgcn_s_setprio(1);
#pragma unroll
        for (int mi = 0; mi < 4; ++mi)
#pragma unroll
            for (int ni = 0; ni < 4; ++ni)
                acc[mi][ni] = __builtin_amdgcn_mfma_f32_16x16x32_bf16(
                    af[mi], bf[ni], acc[mi][ni], 0, 0, 0);
        __builtin_amdgcn_s_setprio(0);
        nb ^= 1;

        if ((t % 10) == 9) {
            const int ms0 = (t / 10) * 128;
            // in-register epilogue: ascending j keeps first-max tie rule
            int jg[4]; bool jvalid[4];
#pragma unroll
            for (int nf = 0; nf < 4; ++nf) {
                const int jl = ms0 + wc0 + nf * 16 + l15;
                jvalid[nf] = (jl < MS);
                jg[nf] = n * MS + jl;
            }
#pragma unroll
            for (int mi = 0; mi < 4; ++mi)
#pragma unroll
                for (int nf = 0; nf < 4; ++nf)
#pragma unroll
                    for (int r = 0; r < 4; ++r) {
                        const int si = mi * 4 + r;
                        float v = jvalid[nf] ? acc[mi][nf][r] : -INFINITY;
                        const bool gt = v > rt0[si];
                        ra[si] = gt ? jg[nf] : ra[si];
                        const float m1 = fminf(rt0[si], v);
                        rt0[si] = fmaxf(rt0[si], v);
                        const float m2 = fminf(rt1[si], m1);
                        rt1[si] = fmaxf(rt1[si], m1);
                        rt2[si] = fmaxf(rt2[si], m2);
                    }
            // re-zero accumulators for the next ms0 block
#pragma unroll
            for (int mi = 0; mi < 4; ++mi)
#pragma unroll
                for (int ni = 0; ni < 4; ++ni)
#pragma unroll
                    for (int r = 0; r < 4; ++r) acc[mi][ni][r] = 0.f;
        }

        __builtin_amdgcn_s_barrier();   // all reads of buffer nb^1 done before
                                        // anyone overwrites it next iteration
    }

    // butterfly merge across the 16 lanes of each col-group (masks 1,2,4,8)
#pragma unroll
    for (int si = 0; si < 16; ++si) {
#pragma unroll
        for (int mask = 1; mask <= 8; mask <<= 1) {
            const float o0 = __shfl_xor(rt0[si], mask);
            const float o1 = __shfl_xor(rt1[si], mask);
            const float o2 = __shfl_xor(rt2[si], mask);
            const int   oa = __shfl_xor(ra[si],  mask);
            const bool take = (o0 > rt0[si]) || (o0 == rt0[si] && oa < ra[si]);
            ra[si] = take ? oa : ra[si];
            float m1 = fminf(rt0[si], o0); rt0[si] = fmaxf(rt0[si], o0);
            float m2 = fminf(rt1[si], m1); rt1[si] = fmaxf(rt1[si], m1);
            rt2[si] = fmaxf(rt2[si], m2);
            m1 = fminf(rt0[si], o1); rt0[si] = fmaxf(rt0[si], o1);
            m2 = fminf(rt1[si], m1); rt1[si] = fmaxf(rt1[si], m1);
            rt2[si] = fmaxf(rt2[si], m2);
            m1 = fminf(rt0[si], o2); rt0[si] = fmaxf(rt0[si], o2);
            m2 = fminf(rt1[si], m1); rt1[si] = fmaxf(rt1[si], m1);
            rt2[si] = fmaxf(rt2[si], m2);
        }
    }

    // select this lane's slot (si == l15)
    float s0 = rt0[0], s1 = rt1[0], s2 = rt2[0]; int sa = ra[0];
#pragma unroll
    for (int i = 1; i < 16; ++i) {
        const bool p = (l15 == i);
        s0 = p ? rt0[i] : s0; s1 = p ? rt1[i] : s1; s2 = p ? rt2[i] : s2; sa = p ? ra[i] : sa;
    }
    const int m = wr0 + (l15 >> 2) * 16 + l4 * 4 + (l15 & 3);

    // cross-wave (col-half) merge via LDS overlay on the dead tile buffers
    __syncthreads();                       // all tile reads done -> safe to overlay
    float4* mbuf = (float4*)&AsBuf[0][0];
    if ((wid >> 1) == 0) {
        float4 v; v.x = s0; v.y = s1; v.z = s2; v.w = __int_as_float(sa);
        mbuf[m] = v;
    }
    __syncthreads();
    if ((wid >> 1) == 1) {
        const float4 o = mbuf[m];
        const int oa = __float_as_int(o.w);
        const bool take = (o.x > s0) || (o.x == s0 && oa < sa);
        sa = take ? oa : sa;
        float m1 = fminf(s0, o.x); s0 = fmaxf(s0, o.x);
        float m2 = fminf(s1, m1);  s1 = fmaxf(s1, m1);
        s2 = fmaxf(s2, m2);
        m1 = fminf(s0, o.y); s0 = fmaxf(s0, o.y);
        m2 = fminf(s1, m1);  s1 = fmaxf(s1, m1);
        s2 = fmaxf(s2, m2);
        m1 = fminf(s0, o.z); s0 = fmaxf(s0, o.z);
        m2 = fminf(s1, m1);  s1 = fmaxf(s1, m1);
        s2 = fmaxf(s2, m2);
        if (m < HW) {
            float4 v; v.x = s0; v.y = s1; v.z = s2; v.w = __int_as_float(sa);
            pout[(bq * NW + n) * HW + m] = v;
        }
    }
#undef STAGE
}

// ---------------------------------------------------------------------------
// Merge 5 per-n partials, mutual-NN mask, logits, per-query CE, atomic mean.
__global__ void merge_kernel(const float4* __restrict__ pout, const int* __restrict__ qy,
                             float* __restrict__ out)
{
    const int bq  = blockIdx.x;
    const int tid = threadIdx.x;   // 128 threads

    __shared__ float cw[128];
    __shared__ int   ag[128];
    __shared__ float tv[NW][128];
    __shared__ float maskf[128];
    __shared__ float lg[8];

    if (tid < HW) {
        float g0 = -INFINITY; int garg = 0;
#pragma unroll
        for (int n = 0; n < NW; ++n) {
            const float4 a = pout[(bq * NW + n) * HW + tid];
            if (a.x > g0) { g0 = a.x; garg = __float_as_int(a.w); }   // asc n = asc j
            tv[n][tid] = (a.x + a.y + a.z) * (1.f / 3.f);
        }
        cw[tid] = g0 + 1.0f;   // class_wise_max
        ag[tid] = garg;        // query_nearest (global j)
    }
    __syncthreads();
    if (tid < HW) {
        const float mycw = cw[tid];
        const int   myag = ag[tid];
        float ok = 1.f;
        for (int m2 = 0; m2 < HW; ++m2) {
            if (m2 == tid) continue;
            if (ag[m2] == myag) {
                float c2 = cw[m2];
                if (c2 > mycw || (c2 == mycw && m2 < tid)) ok = 0.f;  // first-max over mq
            }
        }
        maskf[tid] = ok;
    }
    __syncthreads();
    if (tid < NW) {
        float s = 0.f;
        for (int mq = 0; mq < HW; ++mq) s += maskf[mq] * tv[tid][mq];
        lg[tid] = s * 0.5f;   // / TEMPERATURE
    }
    __syncthreads();
    if (tid == 0) {
        float m = lg[0];
#pragma unroll
        for (int n2 = 1; n2 < NW; ++n2) m = fmaxf(m, lg[n2]);
        float se = 0.f;
#pragma unroll
        for (int n2 = 0; n2 < NW; ++n2) se += expf(lg[n2] - m);
        int y = qy[bq];
        atomicAdd(out, -(lg[y] - m - logf(se)) * (1.f / NBQ));
    }
}

// ---------------------------------------------------------------------------
extern "C" void kernel_launch(void* const* d_in, const int* in_sizes, int n_in,
                              void* d_out, int out_size, void* d_ws, size_t ws_size,
                              hipStream_t stream)
{
    const float* sup = (const float*)d_in[0];   // [4][25][640][121]
    const float* qry = (const float*)d_in[1];   // [4][75][640][121]
    const int*   qy  = (const int*)d_in[3];     // [4][75]
    float* out = (float*)d_out;
    float* ws  = (float*)d_ws;

    __hip_bfloat16* Sbf = (__hip_bfloat16*)(ws + OFF_SBF);
    __hip_bfloat16* Qbf = (__hip_bfloat16*)(ws + OFF_QBF);
    float4* pout = (float4*)(ws + OFF_P);

    hipLaunchKernelGGL(prep_kernel, dim3(BB * SS + NBQ), dim3(256), 0, stream,
                       sup, qry, Sbf, Qbf, out);
    hipLaunchKernelGGL(simi_kernel, dim3(8 * BQ_PER_XCD * NW), dim3(256), 0, stream,
                       Sbf, Qbf, pout);
    hipLaunchKernelGGL(merge_kernel, dim3(NBQ), dim3(128), 0, stream, pout, qy, out);
}

// Round 5
// 395.001 us; speedup vs baseline: 1.2255x; 1.0337x over previous
//
#include <hip/hip_runtime.h>
#include <hip/hip_bf16.h>
#include <math.h>

#define BB 4
#define QQ 75
#define NBQ 300        // BB*QQ
#define CC 640
#define HW 121
#define NW 5
#define KS 5
#define SS 25          // NW*KS
#define MS 605         // KS*HW
#define JT 3025        // NW*MS
#define BQ_PER_XCD 38  // ceil(300/8)

typedef __attribute__((ext_vector_type(8))) short short8;
typedef __attribute__((ext_vector_type(4))) float f32x4;

// workspace float offsets
#define OFF_SBF   0
#define SBF_F     (BB*JT*CC/2)            // bf16 storage
#define OFF_QBF   (OFF_SBF + SBF_F)
#define QBF_F     (NBQ*HW*CC/2)
#define OFF_P     (OFF_QBF + QBF_F)       // float4 partials [300][5][121]

__device__ __forceinline__ void async16(const void* g, void* l) {
    __builtin_amdgcn_global_load_lds(
        (const __attribute__((address_space(1))) unsigned int*)g,
        (__attribute__((address_space(3))) unsigned int*)l, 16, 0, 0);
}

// ---------------------------------------------------------------------------
// Fused: norm (pass 1, HBM-stream, 16 outstanding loads/thread) +
// normalize/cast/transpose (pass 2, cache-hot). One block per descriptor
// column. Output [col][hw][c] bf16. Block 0 also zeroes d_out.
__global__ void prep_kernel(const float* __restrict__ sup, const float* __restrict__ qry,
                            __hip_bfloat16* __restrict__ Sbf, __hip_bfloat16* __restrict__ Qbf,
                            float* __restrict__ out)
{
    const int col = blockIdx.x;      // 0..399
    const int t   = threadIdx.x;     // 256
    if (col == 0 && t == 0) out[0] = 0.f;   // replaces memset dispatch
    const float* src;
    __hip_bfloat16* dst;
    if (col < BB * SS) {
        const int b = col / SS, s = col % SS;
        const int n = s / KS, k = s % KS;
        src = sup + (size_t)col * (CC * HW);
        dst = Sbf + ((size_t)b * JT + n * MS + k * HW) * CC;
    } else {
        const int bq = col - BB * SS;
        src = qry + (size_t)bq * (CC * HW);
        dst = Qbf + (size_t)bq * (HW * CC);
    }

    __shared__ float inv[128];
    __shared__ float T[32][128];

    // ---- phase 1: sum of squares per hw (2 c-interleaved threads, 2 accs) ----
    const int cc2 = t >> 7, hw1 = t & 127;
    float ss0 = 0.f, ss1 = 0.f;
    if (hw1 < HW) {
        const float* p = src + hw1;
#pragma unroll 16
        for (int c = cc2; c < CC; c += 4) {
            float v0 = p[(size_t)c * HW];
            float v1 = p[(size_t)(c + 2) * HW];
            ss0 = fmaf(v0, v0, ss0);
            ss1 = fmaf(v1, v1, ss1);
        }
    }
    T[cc2][hw1] = ss0 + ss1;
    __syncthreads();
    if (t < 128) inv[t] = (t < HW) ? 1.f / (sqrtf(T[0][t] + T[1][t]) + 1e-8f) : 0.f;

    // ---- phase 2: scale + transpose + bf16 write ----
    for (int c0 = 0; c0 < CC; c0 += 32) {
        __syncthreads();
#pragma unroll
        for (int i = 0; i < 16; ++i) {
            int idx = t + i * 256;
            int cc = idx >> 7, hw = idx & 127;
            if (hw < HW) T[cc][hw] = src[(size_t)(c0 + cc) * HW + hw] * inv[hw];
        }
        __syncthreads();
        const int hw = t >> 1, half = t & 1;
        if (hw < HW) {
            __hip_bfloat16 hv[16];
#pragma unroll
            for (int i = 0; i < 16; ++i) hv[i] = __float2bfloat16(T[half * 16 + i][hw]);
            int4* op = reinterpret_cast<int4*>(dst + (size_t)hw * CC + c0 + half * 16);
            op[0] = reinterpret_cast<int4*>(hv)[0];
            op[1] = reinterpret_cast<int4*>(hv)[1];
        }
    }
}

// ---------------------------------------------------------------------------
// Per (bq, n): MFMA cosine GEMM, register-resident top3/argmax.
// R4: TRANSPOSED EPILOGUE. mfma(bf_support, af_query, acc) puts support j on
// the C/D ROW axis and query m on the COL axis: each lane holds 16 j-values
// for just 4 m-slots (m = wm0 + qi*16 + l15; j = ms0+wj0 + ji*16 + l4*4 + r).
// Top-3 over j is a lane-local reduce -> persistent state shrinks 64->16 VGPR,
// which is what killed R2's occupancy push (spill: WRITE 2.8->43 MB).
// With k-chunk 32 (32 KB LDS, R2's verified swizzle) and ~154 combined regs,
// __launch_bounds__(256,3) fits 3 blocks/CU = 12 waves: the counters across
// R1-R3 show no pipe >50% busy and intra-chunk reordering is neutral ->
// cross-chunk latency needs more independent waves, not more ILP.
// Final merge: cross-l4 butterfly (masks 16,32) + 2-way cross-wave LDS merge.
__launch_bounds__(256, 3)
__global__ void simi_kernel(const __hip_bfloat16* __restrict__ Sbf,
                            const __hip_bfloat16* __restrict__ Qbf,
                            float4* __restrict__ pout)
{
    const int xcd   = blockIdx.x & 7;
    const int local = blockIdx.x >> 3;      // 0..189
    const int n     = local % NW;
    const int bq    = xcd * BQ_PER_XCD + local / NW;
    if (bq >= NBQ) return;
    const int b   = bq / QQ;
    const int tid = threadIdx.x;
    const int lane = tid & 63, wid = tid >> 6;
    const int l15 = lane & 15, l4 = lane >> 4;
    const int wj0 = (wid & 1) * 64;    // wave support-row base (tile-local)
    const int wm0 = (wid >> 1) * 64;   // wave query-col base

    const unsigned short* qbase = (const unsigned short*)(Qbf + (size_t)bq * (HW * CC));
    const unsigned short* sbase = (const unsigned short*)(Sbf + ((size_t)b * JT + n * MS) * CC);

    __shared__ __align__(16) unsigned short AsBuf[2][128 * 32];  // query tile, 2 x 8 KB
    __shared__ __align__(16) unsigned short BsBuf[2][128 * 32];  // support tile, 2 x 8 KB

    const int srow = lane >> 2;                       // row within 16-row group
    const int kb   = (lane & 3) ^ ((lane >> 3) & 3);  // swizzled k-block (0..3)
    int aoff2[2];
#pragma unroll
    for (int g = 0; g < 2; ++g) {
        int arow = wid * 32 + g * 16 + srow;
        int grow = arow < HW ? arow : HW - 1;
        aoff2[g] = grow * CC + kb * 8;
    }
    int jb2[2];
#pragma unroll
    for (int g = 0; g < 2; ++g) jb2[g] = wid * 32 + g * 16 + srow;

    const int ldso_base = wid * 2048 + lane * 16;   // byte offset in 8 KB buffer

    // stage one (ms0, c0) chunk (k=32) into buffer nb: 4 async16 per wave
#define STAGE(ms0_, c0_, nb_)                                                        \
    {                                                                                \
        _Pragma("unroll")                                                            \
        for (int g = 0; g < 2; ++g) {                                                \
            const int ldso = ldso_base + g * 1024;                                   \
            async16(qbase + aoff2[g] + (c0_), (char*)&AsBuf[nb_][0] + ldso);         \
            int j_ = (ms0_) + jb2[g];                                                \
            int jc_ = j_ < MS ? j_ : MS - 1;                                         \
            async16(sbase + jc_ * CC + kb * 8 + (c0_), (char*)&BsBuf[nb_][0] + ldso);\
        }                                                                            \
    }

    // per-lane top-3 state: 4 m-slots only (transposed epilogue)
    float rt0[4], rt1[4], rt2[4]; int ra[4];
#pragma unroll
    for (int i = 0; i < 4; ++i) { rt0[i] = -INFINITY; rt1[i] = -INFINITY; rt2[i] = -INFINITY; ra[i] = 0; }

    f32x4 acc[4][4];   // [ji][qi]
#pragma unroll
    for (int ji = 0; ji < 4; ++ji)
#pragma unroll
        for (int qi = 0; qi < 4; ++qi)
#pragma unroll
            for (int r = 0; r < 4; ++r) acc[ji][qi][r] = 0.f;

    // prologue: stage chunk 0
    STAGE(0, 0, 0);
    int nb = 0;

    const int slot = l4 ^ ((l15 >> 1) & 3);           // read slot (0..3)
    const int aro  = (wm0 + l15) * 32 + slot * 8;     // ushort idx, + qi*512
    const int bro  = (wj0 + l15) * 32 + slot * 8;     // ushort idx, + ji*512

    // flat pipelined loop: chunk t -> ms0=(t/20)*128, c0=(t%20)*32
    for (int t = 0; t < 100; ++t) {
        const int tn = t + 1;
        if (tn < 100) {
            const int nms = (tn / 20) * 128;
            const int nc  = (tn % 20) * 32;
            STAGE(nms, nc, nb ^ 1);
            // wait only for chunk-t's 4 loads (issued one full iteration ago)
            asm volatile("s_waitcnt vmcnt(4)" ::: "memory");
        } else {
            asm volatile("s_waitcnt vmcnt(0)" ::: "memory");
        }
        __builtin_amdgcn_s_barrier();   // buffer nb fully resident for all waves

        // ---- compute from buffer nb: 8 fragment reads, 16 MFMA ----
        short8 af[4], bf[4];
#pragma unroll
        for (int qi = 0; qi < 4; ++qi)
            af[qi] = *(const short8*)(&AsBuf[nb][0] + aro + qi * 512);
#pragma unroll
        for (int ji = 0; ji < 4; ++ji)
            bf[ji] = *(const short8*)(&BsBuf[nb][0] + bro + ji * 512);

        __builtin_amdgcn_s_setprio(1);
#pragma unroll
        for (int ji = 0; ji < 4; ++ji)
#pragma unroll
            for (int qi = 0; qi < 4; ++qi)
                acc[ji][qi] = __builtin_amdgcn_mfma_f32_16x16x32_bf16(
                    bf[ji], af[qi], acc[ji][qi], 0, 0, 0);   // D[j, m]
        __builtin_amdgcn_s_setprio(0);
        nb ^= 1;

        if ((t % 20) == 19) {
            const int ms0 = (t / 20) * 128;
            // lane-local top-3 over this pass's 16 j-values per m-slot.
            // (ji, r) ascending == j ascending for fixed lane; strict >
            // keeps the first (smallest-j) max.
#pragma unroll
            for (int qi = 0; qi < 4; ++qi)
#pragma unroll
                for (int ji = 0; ji < 4; ++ji)
#pragma unroll
                    for (int r = 0; r < 4; ++r) {
                        const int jl = ms0 + wj0 + ji * 16 + l4 * 4 + r;
                        float v = (jl < MS) ? acc[ji][qi][r] : -INFINITY;
                        const bool gt = v > rt0[qi];
                        ra[qi] = gt ? (n * MS + jl) : ra[qi];
                        const float m1 = fminf(rt0[qi], v);
                        rt0[qi] = fmaxf(rt0[qi], v);
                        const float m2 = fminf(rt1[qi], m1);
                        rt1[qi] = fmaxf(rt1[qi], m1);
                        rt2[qi] = fmaxf(rt2[qi], m2);
                    }
            // re-zero accumulators for the next ms0 block
#pragma unroll
            for (int ji = 0; ji < 4; ++ji)
#pragma unroll
                for (int qi = 0; qi < 4; ++qi)
#pragma unroll
                    for (int r = 0; r < 4; ++r) acc[ji][qi][r] = 0.f;
        }

        __builtin_amdgcn_s_barrier();   // all reads of buffer nb^1 done before
                                        // anyone overwrites it next iteration
    }

    // cross-l4 butterfly (masks 16,32): merge the 4 j-interleaved partitions
#pragma unroll
    for (int qi = 0; qi < 4; ++qi) {
#pragma unroll
        for (int mask = 16; mask <= 32; mask <<= 1) {
            const float o0 = __shfl_xor(rt0[qi], mask);
            const float o1 = __shfl_xor(rt1[qi], mask);
            const float o2 = __shfl_xor(rt2[qi], mask);
            const int   oa = __shfl_xor(ra[qi],  mask);
            const bool take = (o0 > rt0[qi]) || (o0 == rt0[qi] && oa < ra[qi]);
            ra[qi] = take ? oa : ra[qi];
            float m1 = fminf(rt0[qi], o0); rt0[qi] = fmaxf(rt0[qi], o0);
            float m2 = fminf(rt1[qi], m1); rt1[qi] = fmaxf(rt1[qi], m1);
            rt2[qi] = fmaxf(rt2[qi], m2);
            m1 = fminf(rt0[qi], o1); rt0[qi] = fmaxf(rt0[qi], o1);
            m2 = fminf(rt1[qi], m1); rt1[qi] = fmaxf(rt1[qi], m1);
            rt2[qi] = fmaxf(rt2[qi], m2);
            m1 = fminf(rt0[qi], o2); rt0[qi] = fmaxf(rt0[qi], o2);
            m2 = fminf(rt1[qi], m1); rt1[qi] = fmaxf(rt1[qi], m1);
            rt2[qi] = fmaxf(rt2[qi], m2);
        }
    }

    // cross-wave merge: waves (wid, wid^1) share wm0, hold disjoint j-halves.
    __syncthreads();                       // all tile reads done -> safe overlay
    float4* mbuf = (float4*)&AsBuf[0][0];  // 128 float4 = 2 KB
    if ((wid & 1) == 0 && l4 == 0) {
#pragma unroll
        for (int qi = 0; qi < 4; ++qi) {
            float4 v; v.x = rt0[qi]; v.y = rt1[qi]; v.z = rt2[qi];
            v.w = __int_as_float(ra[qi]);
            mbuf[wm0 + qi * 16 + l15] = v;
        }
    }
    __syncthreads();
    if ((wid & 1) == 1 && l4 == 0) {
#pragma unroll
        for (int qi = 0; qi < 4; ++qi) {
            const int m = wm0 + qi * 16 + l15;
            const float4 o = mbuf[m];
            const int oa = __float_as_int(o.w);
            float s0 = rt0[qi], s1 = rt1[qi], s2 = rt2[qi]; int sa = ra[qi];
            const bool take = (o.x > s0) || (o.x == s0 && oa < sa);
            sa = take ? oa : sa;
            float m1 = fminf(s0, o.x); s0 = fmaxf(s0, o.x);
            float m2 = fminf(s1, m1);  s1 = fmaxf(s1, m1);
            s2 = fmaxf(s2, m2);
            m1 = fminf(s0, o.y); s0 = fmaxf(s0, o.y);
            m2 = fminf(s1, m1);  s1 = fmaxf(s1, m1);
            s2 = fmaxf(s2, m2);
            m1 = fminf(s0, o.z); s0 = fmaxf(s0, o.z);
            m2 = fminf(s1, m1);  s1 = fmaxf(s1, m1);
            s2 = fmaxf(s2, m2);
            if (m < HW) {
                float4 v; v.x = s0; v.y = s1; v.z = s2; v.w = __int_as_float(sa);
                pout[(bq * NW + n) * HW + m] = v;
            }
        }
    }
#undef STAGE
}

// ---------------------------------------------------------------------------
// Merge 5 per-n partials, mutual-NN mask, logits, per-query CE, atomic mean.
__global__ void merge_kernel(const float4* __restrict__ pout, const int* __restrict__ qy,
                             float* __restrict__ out)
{
    const int bq  = blockIdx.x;
    const int tid = threadIdx.x;   // 128 threads

    __shared__ float cw[128];
    __shared__ int   ag[128];
    __shared__ float tv[NW][128];
    __shared__ float maskf[128];
    __shared__ float lg[8];

    if (tid < HW) {
        float g0 = -INFINITY; int garg = 0;
#pragma unroll
        for (int n = 0; n < NW; ++n) {
            const float4 a = pout[(bq * NW + n) * HW + tid];
            if (a.x > g0) { g0 = a.x; garg = __float_as_int(a.w); }   // asc n = asc j
            tv[n][tid] = (a.x + a.y + a.z) * (1.f / 3.f);
        }
        cw[tid] = g0 + 1.0f;   // class_wise_max
        ag[tid] = garg;        // query_nearest (global j)
    }
    __syncthreads();
    if (tid < HW) {
        const float mycw = cw[tid];
        const int   myag = ag[tid];
        float ok = 1.f;
        for (int m2 = 0; m2 < HW; ++m2) {
            if (m2 == tid) continue;
            if (ag[m2] == myag) {
                float c2 = cw[m2];
                if (c2 > mycw || (c2 == mycw && m2 < tid)) ok = 0.f;  // first-max over mq
            }
        }
        maskf[tid] = ok;
    }
    __syncthreads();
    if (tid < NW) {
        float s = 0.f;
        for (int mq = 0; mq < HW; ++mq) s += maskf[mq] * tv[tid][mq];
        lg[tid] = s * 0.5f;   // / TEMPERATURE
    }
    __syncthreads();
    if (tid == 0) {
        float m = lg[0];
#pragma unroll
        for (int n2 = 1; n2 < NW; ++n2) m = fmaxf(m, lg[n2]);
        float se = 0.f;
#pragma unroll
        for (int n2 = 0; n2 < NW; ++n2) se += expf(lg[n2] - m);
        int y = qy[bq];
        atomicAdd(out, -(lg[y] - m - logf(se)) * (1.f / NBQ));
    }
}

// ---------------------------------------------------------------------------
extern "C" void kernel_launch(void* const* d_in, const int* in_sizes, int n_in,
                              void* d_out, int out_size, void* d_ws, size_t ws_size,
                              hipStream_t stream)
{
    const float* sup = (const float*)d_in[0];   // [4][25][640][121]
    const float* qry = (const float*)d_in[1];   // [4][75][640][121]
    const int*   qy  = (const int*)d_in[3];     // [4][75]
    float* out = (float*)d_out;
    float* ws  = (float*)d_ws;

    __hip_bfloat16* Sbf = (__hip_bfloat16*)(ws + OFF_SBF);
    __hip_bfloat16* Qbf = (__hip_bfloat16*)(ws + OFF_QBF);
    float4* pout = (float4*)(ws + OFF_P);

    hipLaunchKernelGGL(prep_kernel, dim3(BB * SS + NBQ), dim3(256), 0, stream,
                       sup, qry, Sbf, Qbf, out);
    hipLaunchKernelGGL(simi_kernel, dim3(8 * BQ_PER_XCD * NW), dim3(256), 0, stream,
                       Sbf, Qbf, pout);
    hipLaunchKernelGGL(merge_kernel, dim3(NBQ), dim3(128), 0, stream, pout, qy, out);
}